// Round 6
// baseline (454.525 us; speedup 1.0000x reference)
//
#include <hip/hip_runtime.h>
#include <math.h>
#include <type_traits>

typedef float f2 __attribute__((ext_vector_type(2)));
typedef float f4 __attribute__((ext_vector_type(4)));

#define DD 160
#define HH 160
#define WW 160
#define BB 4
#define KK 11
#define RAD 5
#define TH 16
#define TW 16
#define DCH 32
#define NPLANES (DCH + 2 * RAD)   // 42 (loop padded to 44 = 2*22)
#define NDCH (DD / DCH)           // 5
#define HALO_H (TH + 2 * RAD)     // 26
#define TS 16                     // tmp row stride: uniform banks (0 conflicts)
#define STAT (HALO_H * TS)        // 416 floats per stat plane

// Weight-pair table in kernarg: gg[2x] = G(x-2), gg[2x+1] = G(x-3); G(j)=g[j] in
// [0,10] else 0. Scalar g[k] = gg[2*(k+2)]. (Proven R5.)
struct GaussP { float gg[32]; };

template <int N> using ic = std::integral_constant<int, N>;

// R5 core + three stall cuts:
//  (1) TWO planes per barrier (37->19 barriers), tmp[4] rotation (plane p -> buf p&3)
//  (2) dual prefetch sets A/B (even/odd planes): issue->use distance ~2 planes,
//      fully covers HBM latency (~900 cyc)
//  (3) balanced phase-1 split: 52 tasks/wave (was 64/40 -> wave1 barrier idle)
// launch_bounds (128,2): allocator budget 256/wave; (128,4) would cap arch at 64 -> spill.
__global__ __launch_bounds__(128, 2)
void ssim3d_kernel(const float* __restrict__ img1,
                   const float* __restrict__ img2,
                   float* __restrict__ out, GaussP gp)
{
    __shared__ float tmp[4][5 * STAT];   // 4-plane rotation, 33.3 KB
    __shared__ float wsum[2];

    const int tid = threadIdx.x;        // 128 threads = 2 waves
    // phase-2 mapping: 16 rows x 8 col-pairs
    const int xc = tid & 7;             // cols 2xc, 2xc+1
    const int ty = tid >> 3;            // 0..15
    // phase-1 mapping (balanced): 104 tasks = 52 per wave
    const int lane = tid & 63;
    const int task = lane + (tid >> 6) * 52;   // wave0: 0..51, wave1: 52..103
    const bool p1act = lane < 52;
    const int p1r = task >> 2;                 // 0..25
    const int p1q = task & 3;

    const int blk = blockIdx.x;
    const int bw = blk % 10;
    const int bh = (blk / 10) % 10;
    const int bd = (blk / 100) % NDCH;
    const int bb = blk / (100 * NDCH);

    const int oh0 = bh * TH, ow0 = bw * TW, od0 = bd * DCH;
    const float* base1 = img1 + (size_t)bb * DD * HH * WW;
    const float* base2 = img2 + (size_t)bb * DD * HH * WW;

    // static D-ring: slot s holds output q with q % 11 == s (f2 = 2 W-cols)
    f2 a1[KK], a2[KK], a11[KK], a22[KK], a12[KK];
#pragma unroll
    for (int i = 0; i < KK; ++i) { a1[i]=0.f; a2[i]=0.f; a11[i]=0.f; a22[i]=0.f; a12[i]=0.f; }

    f2 lsum = 0.f;

    // phase-1 per-thread constants
    const int gh = oh0 - RAD + p1r;
    const bool rowok = p1act && ((unsigned)gh < (unsigned)HH);
    const int gc0 = ow0 + 4 * p1q - 8;                    // first loaded col (16B aligned)
    const size_t rowoff = (size_t)((unsigned)gh < (unsigned)HH ? gh : 0) * WW;

    // dual prefetch sets: A feeds even planes, B feeds odd planes
    f4 paA[5], pbA[5], paB[5], pbB[5];
#pragma unroll
    for (int j = 0; j < 5; ++j) { paA[j]=(f4)0.f; pbA[j]=(f4)0.f; paB[j]=(f4)0.f; pbB[j]=(f4)0.f; }

    auto prefetch = [&](f4* pa, f4* pb, int pn) {
        const int dn = od0 - RAD + pn;
        if (p1act && (pn < NPLANES) && ((unsigned)dn < (unsigned)DD)) {
            const size_t pbv = (size_t)dn * (HH * WW) + rowoff;
#pragma unroll
            for (int j = 0; j < 5; ++j) {
                const int gc = gc0 + 4 * j;
                f4 za = (f4)0.f, zb = (f4)0.f;
                if (rowok && gc >= 0 && gc <= WW - 4) {
                    za = *(const f4*)(base1 + pbv + gc);
                    zb = *(const f4*)(base2 + pbv + gc);
                }
                pa[j] = za; pb[j] = zb;
            }
        }
    };

    // packed W-conv (proven R5): writes 5 stats x 4 cols into tmp[p&3]
    auto phase1 = [&](const f4* pa, const f4* pb, int p) {
        if (!p1act) return;
        f2 q0[5], q1[5];
#pragma unroll
        for (int st = 0; st < 5; ++st) { q0[st] = 0.f; q1[st] = 0.f; }
#pragma unroll
        for (int j = 0; j < 5; ++j) {
#pragma unroll
            for (int ii = 0; ii < 4; ++ii) {
                const int i = 4 * j + ii;          // local col 0..19; need 3..16
                if (i < 3 || i > 16) continue;
                const float av = pa[j][ii], bv = pb[j][ii];
                const float aa = av * av, bb2 = bv * bv, ab = av * bv;
                const f2 w01 = { gp.gg[2*(i-1)], gp.gg[2*(i-1)+1] };
                const f2 w23 = { gp.gg[2*(i-3)], gp.gg[2*(i-3)+1] };
                q0[0] += w01 * av;   q1[0] += w23 * av;
                q0[1] += w01 * bv;   q1[1] += w23 * bv;
                q0[2] += w01 * aa;   q1[2] += w23 * aa;
                q0[3] += w01 * bb2;  q1[3] += w23 * bb2;
                q0[4] += w01 * ab;   q1[4] += w23 * ab;
            }
        }
        float* tw = tmp[p & 3] + p1r * TS + 4 * p1q;   // 16B-aligned
#pragma unroll
        for (int st = 0; st < 5; ++st) {
            f4 v;
            v[0] = q0[st][0]; v[1] = q0[st][1];
            v[2] = q1[st][0]; v[3] = q1[st][1];
            *(f4*)(tw + st * STAT) = v;
        }
    };

    // H-conv + static-slot D scatter for plane p with UU = p % 11 (compile-time)
    auto phase2 = [&](auto ucU, int p) {
        constexpr int UU = decltype(ucU)::value;
        f2 P1 = 0.f, P2 = 0.f, P11 = 0.f, P22 = 0.f, P12 = 0.f;
        const float* tb = tmp[p & 3] + (ty * TS + 2 * xc);
#pragma unroll
        for (int k = 0; k < KK; ++k) {
            const float w = gp.gg[2 * (k + 2)];    // scalar g[k] from SGPR
            const int o = k * TS;
            P1  += w * *(const f2*)(tb + 0*STAT + o);
            P2  += w * *(const f2*)(tb + 1*STAT + o);
            P11 += w * *(const f2*)(tb + 2*STAT + o);
            P22 += w * *(const f2*)(tb + 3*STAT + o);
            P12 += w * *(const f2*)(tb + 4*STAT + o);
        }
#pragma unroll
        for (int t = 0; t < KK; ++t) {
            constexpr int base = UU + 22;
            const int s = (base - t) % 11;         // compile-time fold
            const float w = gp.gg[2 * (t + 2)];
            a1[s]  += w * P1;
            a2[s]  += w * P2;
            a11[s] += w * P11;
            a22[s] += w * P22;
            a12[s] += w * P12;
        }
    };

    // emit output q = p-10 from fixed slot (UU+1)%11, then zero it
    auto emitp = [&](auto ucU, int p) {
        constexpr int UU = decltype(ucU)::value;
        constexpr int e = (UU + 1) % 11;
        if (p >= 2 * RAD && p < NPLANES) {
            f2 mu1 = a1[e], mu2 = a2[e];
            f2 m11 = mu1 * mu1, m22 = mu2 * mu2, m12 = mu1 * mu2;
            f2 sg1 = a11[e] - m11, sg2 = a22[e] - m22, sg12 = a12[e] - m12;
            const float C1c = 0.0001f, C2c = 0.0009f;
            f2 num = (2.f * m12 + C1c) * (2.f * sg12 + C2c);
            f2 den = (m11 + m22 + C1c) * (sg1 + sg2 + C2c);
            lsum += num / den;
        }
        a1[e] = 0.f; a2[e] = 0.f; a11[e] = 0.f; a22[e] = 0.f; a12[e] = 0.f;
    };

    // preamble: A <- plane 0, B <- plane 1
    prefetch(paA, pbA, 0);
    prefetch(paB, pbB, 1);

    int pcbase = 0;
    auto iter = [&](auto ucv) {
        constexpr int V = decltype(ucv)::value;    // 0..10; planes pcbase+2V, +2V+1
        const int p0 = pcbase + 2 * V;
        const int p1 = p0 + 1;
        const int d0 = od0 - RAD + p0;
        const bool dval0 = (p0 < NPLANES) && ((unsigned)d0 < (unsigned)DD);
        const bool dval1 = (p1 < NPLANES) && ((unsigned)(d0 + 1) < (unsigned)DD);

        // phase-1 both planes (separate tmp bufs), re-arm each prefetch set for +2
        if (dval0) phase1(paA, pbA, p0);
        prefetch(paA, pbA, p0 + 2);
        if (dval1) phase1(paB, pbB, p1);
        prefetch(paB, pbB, p1 + 2);

        // ONE barrier per 2 planes; lgkmcnt only (no vmcnt drain; proven R4/R5)
        if (dval0 || dval1) {
            asm volatile("s_waitcnt lgkmcnt(0)\n\ts_barrier" ::: "memory");
        }

        if (dval0) phase2(ic<(2 * V) % 11>{}, p0);
        emitp(ic<(2 * V) % 11>{}, p0);
        if (dval1) phase2(ic<(2 * V + 1) % 11>{}, p1);
        emitp(ic<(2 * V + 1) % 11>{}, p1);
    };

    for (pcbase = 0; pcbase < 44; pcbase += 22) {
        iter(ic<0>{});
        iter(ic<1>{});
        iter(ic<2>{});
        iter(ic<3>{});
        iter(ic<4>{});
        iter(ic<5>{});
        iter(ic<6>{});
        iter(ic<7>{});
        iter(ic<8>{});
        iter(ic<9>{});
        iter(ic<10>{});
    }

    // ---- reduction: wave shuffle -> LDS -> one atomic per block ----
    float v = lsum.x + lsum.y;
#pragma unroll
    for (int off = 32; off > 0; off >>= 1)
        v += __shfl_down(v, off, 64);
    if ((tid & 63) == 0) wsum[tid >> 6] = v;
    __syncthreads();
    if (tid == 0) {
        const float inv_n = 1.0f / ((float)BB * DD * HH * WW);
        atomicAdd(out, (wsum[0] + wsum[1]) * inv_n);
    }
}

extern "C" void kernel_launch(void* const* d_in, const int* in_sizes, int n_in,
                              void* d_out, int out_size, void* d_ws, size_t ws_size,
                              hipStream_t stream) {
    const float* img1 = (const float*)d_in[0];
    const float* img2 = (const float*)d_in[1];
    float* out = (float*)d_out;

    double gd[KK], sum = 0.0;
    for (int i = 0; i < KK; ++i) {
        double x = (double)(i - KK / 2);
        gd[i] = exp(-(x * x) / (2.0 * 1.5 * 1.5));
        sum += gd[i];
    }
    float gf[KK];
    for (int i = 0; i < KK; ++i) gf[i] = (float)(gd[i] / sum);

    GaussP gp;
    for (int x = 0; x < 16; ++x) {
        const int j0 = x - 2, j1 = x - 3;
        gp.gg[2 * x]     = (j0 >= 0 && j0 < KK) ? gf[j0] : 0.0f;
        gp.gg[2 * x + 1] = (j1 >= 0 && j1 < KK) ? gf[j1] : 0.0f;
    }

    hipMemsetAsync(d_out, 0, sizeof(float), stream);

    dim3 grid(10 * 10 * NDCH * BB);   // 2000 blocks
    dim3 block(128);
    hipLaunchKernelGGL(ssim3d_kernel, grid, block, 0, stream,
                       img1, img2, out, gp);
}

// Round 7
// 437.903 us; speedup vs baseline: 1.0380x; 1.0380x over previous
//
#include <hip/hip_runtime.h>
#include <math.h>
#include <type_traits>

typedef float f2 __attribute__((ext_vector_type(2)));
typedef float f4 __attribute__((ext_vector_type(4)));

#define DD 160
#define HH 160
#define WW 160
#define BB 4
#define KK 11
#define RAD 5
#define TH 16
#define TW 8
#define DCH 32
#define NPLANES (DCH + 2 * RAD)   // 42 (loop padded to 44 = 4*11)
#define NDCH (DD / DCH)           // 5
#define HALO_H (TH + 2 * RAD)     // 26
#define TS 20                     // tmp row stride: (10*ty+xc)%32 max 2-way (free)
#define STAT (HALO_H * TS)        // 520 floats per stat plane

// Weight-pair table in kernarg: gg[2x] = G(x-2), gg[2x+1] = G(x-3); G(j)=g[j] in
// [0,10] else 0. Scalar g[k] = gg[2*(k+2)]. (Proven R5.)
struct GaussP { float gg[32]; };

template <int N> using ic = std::integral_constant<int, N>;

// ONE-WAVE workgroups (64 thr), tile 16 rows x 8 cols x 32 planes, 4000 blocks.
// No s_barrier anywhere: DS ops are in-order per wave; lgkmcnt(0) orders the
// phase-1 LDS writes against phase-2 reads. The 2 waves/SIMD (reg-limited) are
// now INDEPENDENT blocks -> latency overlap instead of lockstep barrier stalls.
// Per-lane state identical to R5 champion (ring 110 + one 40-reg prefetch set).
__global__ __launch_bounds__(64, 2)
void ssim3d_kernel(const float* __restrict__ img1,
                   const float* __restrict__ img2,
                   float* __restrict__ out, GaussP gp)
{
    __shared__ float tmp[2][5 * STAT];   // dbuf, 20.8 KB

    const int tid = threadIdx.x;        // 64 threads = 1 wave
    // phase-2 mapping: 16 rows x 4 col-pairs = 64 tasks, 1 per lane
    const int xc = tid & 3;             // cols 2xc, 2xc+1
    const int ty = tid >> 2;            // 0..15
    // phase-1 mapping: 26 rows x 2 quads = 52 tasks (lanes 0..51)
    const int p1r = tid >> 1;           // 0..25 (for tid<52)
    const int p1q = tid & 1;            // quad: output cols 4q..4q+3
    const bool p1act = tid < 52;

    const int blk = blockIdx.x;
    const int bw = blk % 20;
    const int bh = (blk / 20) % 10;
    const int bd = (blk / 200) % NDCH;
    const int bb = blk / 1000;

    const int oh0 = bh * TH, ow0 = bw * TW, od0 = bd * DCH;
    const float* base1 = img1 + (size_t)bb * DD * HH * WW;
    const float* base2 = img2 + (size_t)bb * DD * HH * WW;

    // static D-ring: slot s holds output q with q % 11 == s (f2 = 2 W-cols)
    f2 a1[KK], a2[KK], a11[KK], a22[KK], a12[KK];
#pragma unroll
    for (int i = 0; i < KK; ++i) { a1[i]=0.f; a2[i]=0.f; a11[i]=0.f; a22[i]=0.f; a12[i]=0.f; }

    f2 lsum = 0.f;

    // phase-1 per-thread constants
    const int gh = oh0 - RAD + p1r;
    const bool rowok = p1act && ((unsigned)gh < (unsigned)HH);
    const int gc0 = ow0 + 4 * p1q - 8;                    // first loaded col (16B aligned)
    const size_t rowoff = (size_t)((unsigned)gh < (unsigned)HH ? gh : 0) * WW;

    // prefetch registers for the next plane's 20 cols per lane (5 quads x 2 imgs)
    f4 pa[5], pb[5];
#pragma unroll
    for (int j = 0; j < 5; ++j) { pa[j] = (f4)0.f; pb[j] = (f4)0.f; }

    auto prefetch = [&](int pn) {
        const int dn = od0 - RAD + pn;
        if (p1act && (pn < NPLANES) && ((unsigned)dn < (unsigned)DD)) {
            const size_t pbv = (size_t)dn * (HH * WW) + rowoff;
#pragma unroll
            for (int j = 0; j < 5; ++j) {
                const int gc = gc0 + 4 * j;
                f4 za = (f4)0.f, zb = (f4)0.f;
                if (rowok && gc >= 0 && gc <= WW - 4) {
                    za = *(const f4*)(base1 + pbv + gc);
                    zb = *(const f4*)(base2 + pbv + gc);
                }
                pa[j] = za; pb[j] = zb;
            }
        }
    };

    // preamble: prefetch plane 0
    prefetch(0);

    int pcbase = 0;
    auto body = [&](auto uc) {
        constexpr int U = decltype(uc)::value;
        const int p = pcbase + U;
        const int d = od0 - RAD + p;
        const bool dval = (p < NPLANES) && ((unsigned)d < (unsigned)DD);  // block-uniform

        // ---- phase 1: packed W-conv of 5 stats from prefetched regs (lanes 0..51) ----
        if (dval && p1act) {
            f2 q0[5], q1[5];
#pragma unroll
            for (int st = 0; st < 5; ++st) { q0[st] = 0.f; q1[st] = 0.f; }
#pragma unroll
            for (int j = 0; j < 5; ++j) {
#pragma unroll
                for (int ii = 0; ii < 4; ++ii) {
                    const int i = 4 * j + ii;          // local col 0..19; need 3..16
                    if (i < 3 || i > 16) continue;
                    const float av = pa[j][ii], bv = pb[j][ii];
                    const float aa = av * av, bb2 = bv * bv, ab = av * bv;
                    const f2 w01 = { gp.gg[2*(i-1)], gp.gg[2*(i-1)+1] };
                    const f2 w23 = { gp.gg[2*(i-3)], gp.gg[2*(i-3)+1] };
                    q0[0] += w01 * av;   q1[0] += w23 * av;
                    q0[1] += w01 * bv;   q1[1] += w23 * bv;
                    q0[2] += w01 * aa;   q1[2] += w23 * aa;
                    q0[3] += w01 * bb2;  q1[3] += w23 * bb2;
                    q0[4] += w01 * ab;   q1[4] += w23 * ab;
                }
            }
            float* tw = tmp[p & 1] + p1r * TS + 4 * p1q;   // 16B-aligned (80r+16q bytes)
#pragma unroll
            for (int st = 0; st < 5; ++st) {
                f4 v;
                v[0] = q0[st][0]; v[1] = q0[st][1];
                v[2] = q1[st][0]; v[3] = q1[st][1];
                *(f4*)(tw + st * STAT) = v;
            }
        }

        // ---- prefetch plane p+1 (vmcnt lands at first use, next body) ----
        prefetch(p + 1);

        // ---- phase 2: H-conv (f2, <=2-way banks) + static-slot D scatter ----
        if (dval) {
            // In-order DS per wave + this wait orders phase-1 writes vs reads.
            // NO s_barrier (single-wave workgroup), NO vmcnt drain.
            asm volatile("s_waitcnt lgkmcnt(0)" ::: "memory");
            f2 P1 = 0.f, P2 = 0.f, P11 = 0.f, P22 = 0.f, P12 = 0.f;
            const float* tb = tmp[p & 1] + (ty * TS + 2 * xc);
#pragma unroll
            for (int k = 0; k < KK; ++k) {
                const float w = gp.gg[2 * (k + 2)];    // scalar g[k] from SGPR
                const int o = k * TS;
                P1  += w * *(const f2*)(tb + 0*STAT + o);
                P2  += w * *(const f2*)(tb + 1*STAT + o);
                P11 += w * *(const f2*)(tb + 2*STAT + o);
                P22 += w * *(const f2*)(tb + 3*STAT + o);
                P12 += w * *(const f2*)(tb + 4*STAT + o);
            }
#pragma unroll
            for (int t = 0; t < KK; ++t) {
                constexpr int base = U + 22;
                const int s = (base - t) % 11;         // compile-time fold
                const float w = gp.gg[2 * (t + 2)];
                a1[s]  += w * P1;
                a2[s]  += w * P2;
                a11[s] += w * P11;
                a22[s] += w * P22;
                a12[s] += w * P12;
            }
        }

        // ---- emit output q = p-10 from fixed slot (U+1)%11, then zero it ----
        constexpr int e = (U + 1) % 11;
        if (p >= 2 * RAD && p < NPLANES) {
            f2 mu1 = a1[e], mu2 = a2[e];
            f2 m11 = mu1 * mu1, m22 = mu2 * mu2, m12 = mu1 * mu2;
            f2 sg1 = a11[e] - m11, sg2 = a22[e] - m22, sg12 = a12[e] - m12;
            const float C1c = 0.0001f, C2c = 0.0009f;
            f2 num = (2.f * m12 + C1c) * (2.f * sg12 + C2c);
            f2 den = (m11 + m22 + C1c) * (sg1 + sg2 + C2c);
            lsum += num / den;
        }
        a1[e] = 0.f; a2[e] = 0.f; a11[e] = 0.f; a22[e] = 0.f; a12[e] = 0.f;
    };

    for (pcbase = 0; pcbase < 44; pcbase += 11) {
        body(ic<0>{});
        body(ic<1>{});
        body(ic<2>{});
        body(ic<3>{});
        body(ic<4>{});
        body(ic<5>{});
        body(ic<6>{});
        body(ic<7>{});
        body(ic<8>{});
        body(ic<9>{});
        body(ic<10>{});
    }

    // ---- reduction: single-wave shuffle -> one atomic per block ----
    float v = lsum.x + lsum.y;
#pragma unroll
    for (int off = 32; off > 0; off >>= 1)
        v += __shfl_down(v, off, 64);
    if (tid == 0) {
        const float inv_n = 1.0f / ((float)BB * DD * HH * WW);
        atomicAdd(out, v * inv_n);
    }
}

extern "C" void kernel_launch(void* const* d_in, const int* in_sizes, int n_in,
                              void* d_out, int out_size, void* d_ws, size_t ws_size,
                              hipStream_t stream) {
    const float* img1 = (const float*)d_in[0];
    const float* img2 = (const float*)d_in[1];
    float* out = (float*)d_out;

    double gd[KK], sum = 0.0;
    for (int i = 0; i < KK; ++i) {
        double x = (double)(i - KK / 2);
        gd[i] = exp(-(x * x) / (2.0 * 1.5 * 1.5));
        sum += gd[i];
    }
    float gf[KK];
    for (int i = 0; i < KK; ++i) gf[i] = (float)(gd[i] / sum);

    GaussP gp;
    for (int x = 0; x < 16; ++x) {
        const int j0 = x - 2, j1 = x - 3;
        gp.gg[2 * x]     = (j0 >= 0 && j0 < KK) ? gf[j0] : 0.0f;
        gp.gg[2 * x + 1] = (j1 >= 0 && j1 < KK) ? gf[j1] : 0.0f;
    }

    hipMemsetAsync(d_out, 0, sizeof(float), stream);

    dim3 grid(20 * 10 * NDCH * BB);   // 4000 blocks
    dim3 block(64);                   // 1 wave
    hipLaunchKernelGGL(ssim3d_kernel, grid, block, 0, stream,
                       img1, img2, out, gp);
}

// Round 8
// 331.221 us; speedup vs baseline: 1.3723x; 1.3221x over previous
//
#include <hip/hip_runtime.h>
#include <math.h>
#include <type_traits>

typedef float f2 __attribute__((ext_vector_type(2)));
typedef float f4 __attribute__((ext_vector_type(4)));

#define DD 160
#define HH 160
#define WW 160
#define BB 4
#define KK 11
#define RAD 5
#define TH 16
#define TW 16
#define DCH 32
#define NPLANES (DCH + 2 * RAD)   // 42 (loop padded to 44 = 4*11)
#define NDCH (DD / DCH)           // 5
#define HALO_H (TH + 2 * RAD)     // 26
#define TS 16                     // tmp row stride: 16-lane groups tile 32 banks (R0-proven)
#define STAT (HALO_H * TS)        // 416 floats per stat plane

// Weight-pair table in kernarg: gg[2x] = G(x-2), gg[2x+1] = G(x-3); G(j)=g[j] in
// [0,10] else 0. Scalar g[k] = gg[2*(k+2)]. (Proven R5.)
struct GaussP { float gg[32]; };

template <int N> using ic = std::integral_constant<int, N>;

// R5 champion structure (128 thr, f2 ring/phase-2, reg-prefetch, lgkmcnt-only
// barrier) with the 4-STAT TRANSFORM: u=x1+x2, v=x1-x2; conv fields U,V,A,B
// (A=conv(u^2), B=conv(v^2)) instead of {mu1,mu2,e11,e22,e12}:
//   mu1mu2=(U^2-V^2)/4, m11+m22=(U^2+V^2)/2, e12=(A-B)/4, e11+e22=(A+B)/2.
// -20% phase-2 reads/FMA, ring FMA, LDS traffic; ring regs 110->88.
// Also: balanced phase-1 split (52 tasks/wave; R6-proven mapping).
__global__ __launch_bounds__(128, 2)
void ssim3d_kernel(const float* __restrict__ img1,
                   const float* __restrict__ img2,
                   float* __restrict__ out, GaussP gp)
{
    __shared__ float tmpA[4 * STAT];   // double buffer via pointer swap (13.3 KB total)
    __shared__ float tmpB[4 * STAT];
    __shared__ float wsum[2];

    const int tid = threadIdx.x;        // 128 threads = 2 waves
    // phase-2 mapping: 16 rows x 8 col-pairs
    const int xc = tid & 7;             // cols 2xc, 2xc+1
    const int ty = tid >> 3;            // 0..15
    // phase-1 mapping (balanced): 104 tasks = 52 per wave
    const int lane = tid & 63;
    const int task = lane + (tid >> 6) * 52;   // wave0: 0..51, wave1: 52..103
    const bool p1act = lane < 52;
    const int p1r = task >> 2;                 // 0..25
    const int p1q = task & 3;

    const int blk = blockIdx.x;
    const int bw = blk % 10;
    const int bh = (blk / 10) % 10;
    const int bd = (blk / 100) % NDCH;
    const int bb = blk / (100 * NDCH);

    const int oh0 = bh * TH, ow0 = bw * TW, od0 = bd * DCH;
    const float* base1 = img1 + (size_t)bb * DD * HH * WW;
    const float* base2 = img2 + (size_t)bb * DD * HH * WW;

    // static D-ring: slot s holds output q with q % 11 == s (f2 = 2 W-cols)
    f2 aU[KK], aV[KK], aA[KK], aB[KK];
#pragma unroll
    for (int i = 0; i < KK; ++i) { aU[i]=0.f; aV[i]=0.f; aA[i]=0.f; aB[i]=0.f; }

    f2 lsum = 0.f;

    // phase-1 per-thread constants
    const int gh = oh0 - RAD + p1r;
    const bool rowok = p1act && ((unsigned)gh < (unsigned)HH);
    const int gc0 = ow0 + 4 * p1q - 8;                    // first loaded col (16B aligned)
    const size_t rowoff = (size_t)((unsigned)gh < (unsigned)HH ? gh : 0) * WW;

    // prefetch registers for the next plane's 20 cols per thread
    f4 pa[5], pb[5];
#pragma unroll
    for (int j = 0; j < 5; ++j) { pa[j] = (f4)0.f; pb[j] = (f4)0.f; }

    float* twr = tmpA;   // buffer written (and read) this plane
    float* trd = tmpB;   // buffer of the previous plane

    auto prefetch = [&](int pn) {
        const int dn = od0 - RAD + pn;
        if (p1act && (pn < NPLANES) && ((unsigned)dn < (unsigned)DD)) {
            const size_t pbv = (size_t)dn * (HH * WW) + rowoff;
#pragma unroll
            for (int j = 0; j < 5; ++j) {
                const int gc = gc0 + 4 * j;
                f4 za = (f4)0.f, zb = (f4)0.f;
                if (rowok && gc >= 0 && gc <= WW - 4) {
                    za = *(const f4*)(base1 + pbv + gc);
                    zb = *(const f4*)(base2 + pbv + gc);
                }
                pa[j] = za; pb[j] = zb;
            }
        }
    };

    // preamble: prefetch plane p=0 if valid
    prefetch(0);

    int pcbase = 0;
    auto body = [&](auto uc) {
        constexpr int U = decltype(uc)::value;
        const int p = pcbase + U;
        const int d = od0 - RAD + p;
        const bool dval = (p < NPLANES) && ((unsigned)d < (unsigned)DD);  // block-uniform

        // ---- phase 1: packed W-conv of 4 transformed stats (52 tasks/wave) ----
        if (dval && p1act) {
            // q0[st] = outputs (0,1), q1[st] = outputs (2,3); st: U,V,A,B
            f2 q0[4], q1[4];
#pragma unroll
            for (int st = 0; st < 4; ++st) { q0[st] = 0.f; q1[st] = 0.f; }
#pragma unroll
            for (int j = 0; j < 5; ++j) {
#pragma unroll
                for (int ii = 0; ii < 4; ++ii) {
                    const int i = 4 * j + ii;          // local col 0..19; need 3..16
                    if (i < 3 || i > 16) continue;
                    const float av = pa[j][ii], bv = pb[j][ii];
                    const float uv = av + bv, vv = av - bv;
                    const float uu = uv * uv, w2 = vv * vv;
                    // pair (t0,t1): taps (i-3, i-4) -> gg[i-1]; pair (t2,t3): gg[i-3]
                    const f2 w01 = { gp.gg[2*(i-1)], gp.gg[2*(i-1)+1] };
                    const f2 w23 = { gp.gg[2*(i-3)], gp.gg[2*(i-3)+1] };
                    q0[0] += w01 * uv;   q1[0] += w23 * uv;
                    q0[1] += w01 * vv;   q1[1] += w23 * vv;
                    q0[2] += w01 * uu;   q1[2] += w23 * uu;
                    q0[3] += w01 * w2;   q1[3] += w23 * w2;
                }
            }
            float* tw = twr + p1r * TS + 4 * p1q;      // 16B-aligned
#pragma unroll
            for (int st = 0; st < 4; ++st) {
                f4 v;
                v[0] = q0[st][0]; v[1] = q0[st][1];
                v[2] = q1[st][0]; v[3] = q1[st][1];
                *(f4*)(tw + st * STAT) = v;
            }
        }

        // ---- prefetch plane p+1 (vmcnt lands at first use, next body) ----
        prefetch(p + 1);

        // ---- phase 2: H-conv (f2, conflict-free) + static-slot D scatter ----
        if (dval) {
            // Raw barrier: order LDS tmp traffic only (lgkmcnt); no vmcnt drain.
            asm volatile("s_waitcnt lgkmcnt(0)\n\ts_barrier" ::: "memory");
            f2 PU = 0.f, PV = 0.f, PA = 0.f, PB = 0.f;
            const float* tb = twr + (ty * TS + 2 * xc);
#pragma unroll
            for (int k = 0; k < KK; ++k) {
                const float w = gp.gg[2 * (k + 2)];    // scalar g[k] from SGPR
                const int o = k * TS;
                PU += w * *(const f2*)(tb + 0*STAT + o);
                PV += w * *(const f2*)(tb + 1*STAT + o);
                PA += w * *(const f2*)(tb + 2*STAT + o);
                PB += w * *(const f2*)(tb + 3*STAT + o);
            }
#pragma unroll
            for (int t = 0; t < KK; ++t) {
                constexpr int base = U + 22;
                const int s = (base - t) % 11;         // compile-time fold
                const float w = gp.gg[2 * (t + 2)];
                aU[s] += w * PU;
                aV[s] += w * PV;
                aA[s] += w * PA;
                aB[s] += w * PB;
            }
        }

        // ---- emit output q = p-10 from fixed slot (U+1)%11, then zero it ----
        constexpr int e = (U + 1) % 11;
        if (p >= 2 * RAD && p < NPLANES) {
            f2 Uv = aU[e], Vv = aV[e], Av = aA[e], Bv = aB[e];
            f2 U2 = Uv * Uv, V2 = Vv * Vv;
            f2 m12  = 0.25f * (U2 - V2);    // mu1*mu2
            f2 msum = 0.50f * (U2 + V2);    // mu1^2 + mu2^2
            f2 e12  = 0.25f * (Av - Bv);    // E[x1 x2]
            f2 esum = 0.50f * (Av + Bv);    // E[x1^2] + E[x2^2]
            f2 sg12 = e12 - m12;
            f2 sgsum = esum - msum;
            const float C1c = 0.0001f, C2c = 0.0009f;
            f2 num = (2.f * m12 + C1c) * (2.f * sg12 + C2c);
            f2 den = (msum + C1c) * (sgsum + C2c);
            lsum += num / den;
        }
        aU[e] = 0.f; aV[e] = 0.f; aA[e] = 0.f; aB[e] = 0.f;

        // swap double buffers
        float* t = twr; twr = trd; trd = t;
    };

    for (pcbase = 0; pcbase < 44; pcbase += 11) {
        body(ic<0>{});
        body(ic<1>{});
        body(ic<2>{});
        body(ic<3>{});
        body(ic<4>{});
        body(ic<5>{});
        body(ic<6>{});
        body(ic<7>{});
        body(ic<8>{});
        body(ic<9>{});
        body(ic<10>{});
    }

    // ---- reduction: wave shuffle -> LDS -> one atomic per block ----
    float v = lsum.x + lsum.y;
#pragma unroll
    for (int off = 32; off > 0; off >>= 1)
        v += __shfl_down(v, off, 64);
    if ((tid & 63) == 0) wsum[tid >> 6] = v;
    __syncthreads();
    if (tid == 0) {
        const float inv_n = 1.0f / ((float)BB * DD * HH * WW);
        atomicAdd(out, (wsum[0] + wsum[1]) * inv_n);
    }
}

extern "C" void kernel_launch(void* const* d_in, const int* in_sizes, int n_in,
                              void* d_out, int out_size, void* d_ws, size_t ws_size,
                              hipStream_t stream) {
    const float* img1 = (const float*)d_in[0];
    const float* img2 = (const float*)d_in[1];
    float* out = (float*)d_out;

    double gd[KK], sum = 0.0;
    for (int i = 0; i < KK; ++i) {
        double x = (double)(i - KK / 2);
        gd[i] = exp(-(x * x) / (2.0 * 1.5 * 1.5));
        sum += gd[i];
    }
    float gf[KK];
    for (int i = 0; i < KK; ++i) gf[i] = (float)(gd[i] / sum);

    GaussP gp;
    for (int x = 0; x < 16; ++x) {
        const int j0 = x - 2, j1 = x - 3;
        gp.gg[2 * x]     = (j0 >= 0 && j0 < KK) ? gf[j0] : 0.0f;
        gp.gg[2 * x + 1] = (j1 >= 0 && j1 < KK) ? gf[j1] : 0.0f;
    }

    hipMemsetAsync(d_out, 0, sizeof(float), stream);

    dim3 grid(10 * 10 * NDCH * BB);   // 2000 blocks
    dim3 block(128);
    hipLaunchKernelGGL(ssim3d_kernel, grid, block, 0, stream,
                       img1, img2, out, gp);
}

// Round 11
// 312.379 us; speedup vs baseline: 1.4550x; 1.0603x over previous
//
#include <hip/hip_runtime.h>
#include <math.h>
#include <type_traits>

typedef float f2 __attribute__((ext_vector_type(2)));
typedef float f4 __attribute__((ext_vector_type(4)));

#define DD 160
#define HH 160
#define WW 160
#define BB 4
#define KK 11
#define RAD 5
#define TH 16
#define TW 16
#define DCH 32
#define NPLANES (DCH + 2 * RAD)   // 42 planes per tile (loop padded to 44 = 4*11)
#define NDCH (DD / DCH)           // 5 depth chunks
#define HALO_H (TH + 2 * RAD)     // 26 halo rows
#define TS 16                     // tmp row stride; 16-lane groups tile all 32 banks
#define STAT (HALO_H * TS)        // 416 floats per convolved field plane

// Kernarg weight-pair table: gg[2x] = G(x-2), gg[2x+1] = G(x-3), where G(j) is
// the Gaussian tap for j in [0,10] and 0 outside. Scalar tap g[k] = gg[2*(k+2)].
struct GaussP { float gg[32]; };

template <int N> using ic = std::integral_constant<int, N>;

// Base: R8 champion (4-field transform u=x1+x2, v=x1-x2 -> conv fields U,V,A,B;
// f2-packed ring and H-conv; register prefetch; lgkmcnt-only plane barrier).
// Delta under test: XCD-chunked blockIdx swizzle. Default dispatch round-robins
// the 8 XCDs, scattering halo-sharing neighbor tiles across non-coherent L2s;
// measured FETCH (379 MB) is ~2.9x the 131 MB ideal, i.e. halo re-reads come
// from HBM (~900 cyc) and exceed the ~700-cyc prefetch cover distance. The
// chunked remap hands each XCD 250 consecutive tiles (~850 KB working set,
// well under 4 MB L2), converting halo re-reads into L2 hits.
__global__ __launch_bounds__(128, 2)
void ssim3d_kernel(const float* __restrict__ img1,
                   const float* __restrict__ img2,
                   float* __restrict__ out, GaussP gp)
{
    __shared__ float tmpA[4 * STAT];   // plane double buffer (pointer swap), 13.3 KB
    __shared__ float tmpB[4 * STAT];
    __shared__ float wsum[2];

    const int tid = threadIdx.x;        // 128 threads = 2 waves
    const int xc = tid & 7;             // phase-2: col pair 2xc, 2xc+1
    const int ty = tid >> 3;            // phase-2: row 0..15
    const int lane = tid & 63;          // phase-1: 52 tasks per wave (balanced)
    const int task = lane + (tid >> 6) * 52;
    const bool p1act = lane < 52;
    const int p1r = task >> 2;          // halo row 0..25
    const int p1q = task & 3;           // quad index

    // XCD-chunked swizzle (bijective: 2000 blocks, 2000 % 8 == 0).
    const int blk0 = blockIdx.x;
    const int blk = (blk0 & 7) * 250 + (blk0 >> 3);
    const int bw = blk % 10;
    const int bh = (blk / 10) % 10;
    const int bd = (blk / 100) % NDCH;
    const int bb = blk / (100 * NDCH);

    const int oh0 = bh * TH, ow0 = bw * TW, od0 = bd * DCH;
    const float* base1 = img1 + (size_t)bb * DD * HH * WW;
    const float* base2 = img2 + (size_t)bb * DD * HH * WW;

    // Static D-ring: slot s accumulates output plane q with q % 11 == s.
    f2 aU[KK], aV[KK], aA[KK], aB[KK];
#pragma unroll
    for (int i = 0; i < KK; ++i) { aU[i]=0.f; aV[i]=0.f; aA[i]=0.f; aB[i]=0.f; }

    f2 lsum = 0.f;

    // Phase-1 per-thread constants.
    const int gh = oh0 - RAD + p1r;
    const bool rowok = p1act && ((unsigned)gh < (unsigned)HH);
    const int gc0 = ow0 + 4 * p1q - 8;                    // first loaded col, 16B aligned
    const size_t rowoff = (size_t)((unsigned)gh < (unsigned)HH ? gh : 0) * WW;

    // Register prefetch for the next plane (20 cols per thread, both images).
    f4 pa[5], pb[5];
#pragma unroll
    for (int j = 0; j < 5; ++j) { pa[j] = (f4)0.f; pb[j] = (f4)0.f; }

    float* twr = tmpA;   // written (and read) this plane
    float* trd = tmpB;   // previous plane's buffer

    auto prefetch = [&](int pn) {
        const int dn = od0 - RAD + pn;
        if (p1act && (pn < NPLANES) && ((unsigned)dn < (unsigned)DD)) {
            const size_t pbv = (size_t)dn * (HH * WW) + rowoff;
#pragma unroll
            for (int j = 0; j < 5; ++j) {
                const int gc = gc0 + 4 * j;
                f4 za = (f4)0.f, zb = (f4)0.f;
                if (rowok && gc >= 0 && gc <= WW - 4) {
                    za = *(const f4*)(base1 + pbv + gc);
                    zb = *(const f4*)(base2 + pbv + gc);
                }
                pa[j] = za; pb[j] = zb;
            }
        }
    };

    prefetch(0);   // preamble: plane 0

    int pcbase = 0;
    auto body = [&](auto uc) {
        constexpr int U = decltype(uc)::value;
        const int p = pcbase + U;
        const int d = od0 - RAD + p;
        const bool dval = (p < NPLANES) && ((unsigned)d < (unsigned)DD);  // uniform

        // Phase 1: W-direction conv of the 4 transformed fields (52 tasks/wave).
        if (dval && p1act) {
            f2 q0[4], q1[4];   // q0 -> output cols (0,1); q1 -> (2,3)
#pragma unroll
            for (int st = 0; st < 4; ++st) { q0[st] = 0.f; q1[st] = 0.f; }
#pragma unroll
            for (int j = 0; j < 5; ++j) {
#pragma unroll
                for (int ii = 0; ii < 4; ++ii) {
                    const int i = 4 * j + ii;          // window col 0..19; use 3..16
                    if (i < 3 || i > 16) continue;
                    const float av = pa[j][ii], bv = pb[j][ii];
                    const float uv = av + bv, vv = av - bv;
                    const float uu = uv * uv, w2 = vv * vv;
                    const f2 w01 = { gp.gg[2*(i-1)], gp.gg[2*(i-1)+1] };
                    const f2 w23 = { gp.gg[2*(i-3)], gp.gg[2*(i-3)+1] };
                    q0[0] += w01 * uv;   q1[0] += w23 * uv;
                    q0[1] += w01 * vv;   q1[1] += w23 * vv;
                    q0[2] += w01 * uu;   q1[2] += w23 * uu;
                    q0[3] += w01 * w2;   q1[3] += w23 * w2;
                }
            }
            float* tw = twr + p1r * TS + 4 * p1q;      // 16B-aligned store base
#pragma unroll
            for (int st = 0; st < 4; ++st) {
                f4 v;
                v[0] = q0[st][0]; v[1] = q0[st][1];
                v[2] = q1[st][0]; v[3] = q1[st][1];
                *(f4*)(tw + st * STAT) = v;
            }
        }

        // Prefetch plane p+1; its waitcnt lands at first use in the next body.
        prefetch(p + 1);

        // Phase 2: H-direction conv (f2, conflict-free) + static-slot D scatter.
        if (dval) {
            // Order only LDS traffic; no vmcnt drain (prefetch completes later).
            asm volatile("s_waitcnt lgkmcnt(0)\n\ts_barrier" ::: "memory");
            f2 PU = 0.f, PV = 0.f, PA = 0.f, PB = 0.f;
            const float* tb = twr + (ty * TS + 2 * xc);
#pragma unroll
            for (int k = 0; k < KK; ++k) {
                const float w = gp.gg[2 * (k + 2)];    // scalar tap from SGPR
                const int o = k * TS;
                PU += w * *(const f2*)(tb + 0*STAT + o);
                PV += w * *(const f2*)(tb + 1*STAT + o);
                PA += w * *(const f2*)(tb + 2*STAT + o);
                PB += w * *(const f2*)(tb + 3*STAT + o);
            }
#pragma unroll
            for (int t = 0; t < KK; ++t) {
                constexpr int base = U + 22;
                const int s = (base - t) % 11;         // compile-time slot fold
                const float w = gp.gg[2 * (t + 2)];
                aU[s] += w * PU;
                aV[s] += w * PV;
                aA[s] += w * PA;
                aB[s] += w * PB;
            }
        }

        // Emit output plane q = p-10 from slot (U+1)%11, then clear the slot.
        constexpr int e = (U + 1) % 11;
        if (p >= 2 * RAD && p < NPLANES) {
            f2 Uv = aU[e], Vv = aV[e], Av = aA[e], Bv = aB[e];
            f2 U2 = Uv * Uv, V2 = Vv * Vv;
            f2 m12  = 0.25f * (U2 - V2);    // mu1*mu2
            f2 msum = 0.50f * (U2 + V2);    // mu1^2 + mu2^2
            f2 e12  = 0.25f * (Av - Bv);    // E[x1 x2]
            f2 esum = 0.50f * (Av + Bv);    // E[x1^2] + E[x2^2]
            f2 sg12 = e12 - m12;
            f2 sgsum = esum - msum;
            const float C1c = 0.0001f, C2c = 0.0009f;
            f2 num = (2.f * m12 + C1c) * (2.f * sg12 + C2c);
            f2 den = (msum + C1c) * (sgsum + C2c);
            lsum += num / den;
        }
        aU[e] = 0.f; aV[e] = 0.f; aA[e] = 0.f; aB[e] = 0.f;

        float* t = twr; twr = trd; trd = t;   // swap plane buffers
    };

    for (pcbase = 0; pcbase < 44; pcbase += 11) {
        body(ic<0>{});
        body(ic<1>{});
        body(ic<2>{});
        body(ic<3>{});
        body(ic<4>{});
        body(ic<5>{});
        body(ic<6>{});
        body(ic<7>{});
        body(ic<8>{});
        body(ic<9>{});
        body(ic<10>{});
    }

    // Reduction: wave shuffle -> LDS -> one atomic per block.
    float v = lsum.x + lsum.y;
#pragma unroll
    for (int off = 32; off > 0; off >>= 1)
        v += __shfl_down(v, off, 64);
    if ((tid & 63) == 0) wsum[tid >> 6] = v;
    __syncthreads();
    if (tid == 0) {
        const float inv_n = 1.0f / ((float)BB * DD * HH * WW);
        atomicAdd(out, (wsum[0] + wsum[1]) * inv_n);
    }
}

extern "C" void kernel_launch(void* const* d_in, const int* in_sizes, int n_in,
                              void* d_out, int out_size, void* d_ws, size_t ws_size,
                              hipStream_t stream) {
    const float* img1 = (const float*)d_in[0];
    const float* img2 = (const float*)d_in[1];
    float* out = (float*)d_out;

    double gd[KK], sum = 0.0;
    for (int i = 0; i < KK; ++i) {
        double x = (double)(i - KK / 2);
        gd[i] = exp(-(x * x) / (2.0 * 1.5 * 1.5));
        sum += gd[i];
    }
    float gf[KK];
    for (int i = 0; i < KK; ++i) gf[i] = (float)(gd[i] / sum);

    GaussP gp;
    for (int x = 0; x < 16; ++x) {
        const int j0 = x - 2, j1 = x - 3;
        gp.gg[2 * x]     = (j0 >= 0 && j0 < KK) ? gf[j0] : 0.0f;
        gp.gg[2 * x + 1] = (j1 >= 0 && j1 < KK) ? gf[j1] : 0.0f;
    }

    hipMemsetAsync(d_out, 0, sizeof(float), stream);

    dim3 grid(10 * 10 * NDCH * BB);   // 2000 blocks; % 8 XCDs == 0 (bijective swizzle)
    dim3 block(128);
    hipLaunchKernelGGL(ssim3d_kernel, grid, block, 0, stream,
                       img1, img2, out, gp);
}